// Round 8
// baseline (112.228 us; speedup 1.0000x reference)
//
#include <hip/hip_runtime.h>

// VectorQuantizer R7: input (16,64,64,64) f32 channel-first, codebook (1024,64) f32.
// out = [quantized (16,64,64,64) f32 | indices (16,64,64) as f32].
//
// A = codebook split-f16 (-2c hi/lo + esq hi/lo 9th chunk), B = tokens split-f16,
// mfma_f32_32x32x16_f16 3-pass (hi*hi + hi*lo + lo*hi) -> score err ~6e-5.
// R7 structure: block = 256 thr / 4 waves / 128 tokens; wave (g,h) = token-half x
// K-half (16 tiles). Grid 512 -> 2 blocks/CU, 2 waves/SIMD, zero hot-loop barriers.
// Tile rotation (blockIdx&15) decorrelates the shared A-stream across blocks.
// Packed-slot top-2 tracking (3 VALU/score, 8-bit slot, pert <=2.4e-4), exact-gap
// near-ties (EPS=2e-3) -> block-cooperative exact fp32 rescan (~16 tokens chip).

typedef _Float16 v8h  __attribute__((ext_vector_type(8)));
typedef float    v16f __attribute__((ext_vector_type(16)));

constexpr int   D         = 64;
constexpr int   K         = 1024;
constexpr int   HW        = 4096;
constexpr int   DHW       = D * HW;
constexpr int   OUT_ELEMS = 16 * DHW;
constexpr float EPS       = 2e-3f;

// CH: 32 tiles x 9 chunks x 64 lanes x 8 f16 = 288 KB.
// frag f = t*9+kc; CH[f*512 + lane*8 + j]:
//   kc 0-3: hi of -2*C[row = t*32+(lane&31)][k = kc*16+(lane>>5)*8+j]
//   kc 4-7: lo of same
//   kc 8  : lh==0: j0=e_hi, j1=e_lo (pairs with B5 = ones at k=0,1)

__global__ __launch_bounds__(256) void vq_prep(
    const float* __restrict__ cb, _Float16* __restrict__ CH, float* __restrict__ esq)
{
    const int blk = blockIdx.x, tid = threadIdx.x;
    if (blk < 72) {
        const int gid  = blk * 256 + tid;          // [0, 18432)
        const int lane = gid & 63;
        const int fid  = gid >> 6;                 // [0, 288)
        const int t    = fid / 9;
        const int kc   = fid - 9 * t;
        const int l31  = lane & 31;
        const int lh   = lane >> 5;
        const int cw   = t * 32 + l31;
        v8h h;
        if (kc < 8) {
            const int  kk = kc & 3;
            const bool lo = kc >= 4;
            const float* src = cb + cw * D + kk * 16 + lh * 8;
            #pragma unroll
            for (int j = 0; j < 8; ++j) {
                const float v = -2.0f * src[j];
                const _Float16 vh = (_Float16)v;
                h[j] = lo ? (_Float16)(v - (float)vh) : vh;
            }
        } else {
            #pragma unroll
            for (int j = 0; j < 8; ++j) h[j] = (_Float16)0.0f;
            if (lh == 0) {
                const float4* c4 = (const float4*)(cb + cw * D);
                float a0 = 0.f, a1 = 0.f, a2 = 0.f, a3 = 0.f;
                #pragma unroll
                for (int j = 0; j < 16; ++j) {
                    const float4 c = c4[j];
                    a0 = fmaf(c.x, c.x, a0);
                    a1 = fmaf(c.y, c.y, a1);
                    a2 = fmaf(c.z, c.z, a2);
                    a3 = fmaf(c.w, c.w, a3);
                }
                const float e = (a0 + a1) + (a2 + a3);
                const _Float16 ehi = (_Float16)e;
                h[0] = ehi;
                h[1] = (_Float16)(e - (float)ehi);
            }
        }
        *(v8h*)(CH + (size_t)fid * 512 + lane * 8) = h;
    } else {
        const int cw = (blk - 72) * 256 + tid;     // exact f32 e_sq for rescan
        const float4* c4 = (const float4*)(cb + cw * D);
        float a0 = 0.f, a1 = 0.f, a2 = 0.f, a3 = 0.f;
        #pragma unroll
        for (int j = 0; j < 16; ++j) {
            const float4 c = c4[j];
            a0 = fmaf(c.x, c.x, a0);
            a1 = fmaf(c.y, c.y, a1);
            a2 = fmaf(c.z, c.z, a2);
            a3 = fmaf(c.w, c.w, a3);
        }
        esq[cw] = (a0 + a1) + (a2 + a3);
    }
}

__global__ __launch_bounds__(256, 2) void vq_scan(
    const float* __restrict__ input,
    const float* __restrict__ codebook,
    const _Float16* __restrict__ CH,
    const float* __restrict__ esq,
    float* __restrict__ out)
{
    __shared__ _Float16 s_bf[2][2][2][4][64][8]; // [g][hi/lo][ct][kc][lane][8], 32 KB
    __shared__ float    s_pv[2][2][64];          // [h][g][tok] best (packed)
    __shared__ float    s_p2[2][2][64];
    __shared__ int      s_pk[2][2][64];
    __shared__ int      s_idx[128];
    __shared__ int      s_list[128];
    __shared__ int      s_cnt;
    __shared__ float    s_xf[64];
    __shared__ float    s_redv[4];
    __shared__ int      s_redk[4];

    const int tid  = threadIdx.x;
    const int lane = tid & 63;
    const int q    = __builtin_amdgcn_readfirstlane(tid >> 6);
    const int g    = q >> 1;               // token half
    const int h    = q & 1;                // K half (16 tiles)
    const int lh   = lane >> 5;
    const int tok0 = blockIdx.x * 128;
    const int b    = tok0 >> 12;
    const int hwb  = tok0 & 4095;
    const int rot  = blockIdx.x & 15;      // tile rotation: decorrelate A-stream

    if (tid == 0) s_cnt = 0;

    // ---- cooperative B staging: 128 tokens x 64 ch, float4, hi/lo split ----
    {
        const float* xb = input + (size_t)b * DHW + hwb;
        #pragma unroll
        for (int pass = 0; pass < 8; ++pass) {
            const int d   = pass * 8 + (tid >> 5);
            const int hw4 = (tid & 31) * 4;
            const float4 v = *(const float4*)(xb + (size_t)d * HW + hw4);
            const float vv[4] = {v.x, v.y, v.z, v.w};
            #pragma unroll
            for (int u = 0; u < 4; ++u) {
                const int tk  = hw4 + u;
                const int gg  = tk >> 6;
                const int tl6 = tk & 63;
                const float f = vv[u];
                const _Float16 fh = (_Float16)f;
                s_bf[gg][0][tl6 >> 5][d >> 4][((d >> 3) & 1) * 32 + (tl6 & 31)][d & 7] = fh;
                s_bf[gg][1][tl6 >> 5][d >> 4][((d >> 3) & 1) * 32 + (tl6 & 31)][d & 7] =
                    (_Float16)(f - (float)fh);
            }
        }
    }
    __syncthreads();

    // ---- B fragments from LDS ----
    v8h bh[2][4], bl[2][4];
    #pragma unroll
    for (int ct = 0; ct < 2; ++ct)
        #pragma unroll
        for (int kc = 0; kc < 4; ++kc) {
            bh[ct][kc] = *(const v8h*)&s_bf[g][0][ct][kc][lane][0];
            bl[ct][kc] = *(const v8h*)&s_bf[g][1][ct][kc][lane][0];
        }

    // B5: ones at k=0,1 (pairs with esq chunk)
    v8h b5;
    #pragma unroll
    for (int j = 0; j < 8; ++j) b5[j] = (_Float16)0.0f;
    if (lh == 0) { b5[0] = (_Float16)1.0f; b5[1] = (_Float16)1.0f; }

    v16f Z = {0,0,0,0,0,0,0,0,0,0,0,0,0,0,0,0};
    const float INF = __builtin_huge_valf();
    float bv0 = INF, b20 = INF, bv1 = INF, b21 = INF;

    const v8h* Abase = (const v8h*)CH + lane;

    // ---- hot loop: 16 tiles (rotated), explicit register double-buffer ----
    v8h a0, a1, a2, a3, a4, a5, a6, a7, ae;
    {
        const int T0 = h * 16 + rot;
        const v8h* Ap = Abase + (size_t)(T0 * 9) * 64;
        a0 = Ap[0];   a1 = Ap[64];  a2 = Ap[128]; a3 = Ap[192];
        a4 = Ap[256]; a5 = Ap[320]; a6 = Ap[384]; a7 = Ap[448];
        ae = Ap[512];
    }
    #pragma unroll 1
    for (int i = 0; i < 16; ++i) {
        const int tn = (i < 15) ? ((rot + i + 1) & 15) : rot;
        const v8h* Apn = Abase + (size_t)((h * 16 + tn) * 9) * 64;
        v8h n0 = Apn[0],   n1 = Apn[64],  n2 = Apn[128], n3 = Apn[192];
        v8h n4 = Apn[256], n5 = Apn[320], n6 = Apn[384], n7 = Apn[448];
        v8h ne = Apn[512];

        v16f acc0 = __builtin_amdgcn_mfma_f32_32x32x16_f16(ae, b5, Z, 0, 0, 0);
        v16f acc1 = __builtin_amdgcn_mfma_f32_32x32x16_f16(ae, b5, Z, 0, 0, 0);

        acc0 = __builtin_amdgcn_mfma_f32_32x32x16_f16(a0, bh[0][0], acc0, 0, 0, 0);
        acc1 = __builtin_amdgcn_mfma_f32_32x32x16_f16(a0, bh[1][0], acc1, 0, 0, 0);
        acc0 = __builtin_amdgcn_mfma_f32_32x32x16_f16(a1, bh[0][1], acc0, 0, 0, 0);
        acc1 = __builtin_amdgcn_mfma_f32_32x32x16_f16(a1, bh[1][1], acc1, 0, 0, 0);
        acc0 = __builtin_amdgcn_mfma_f32_32x32x16_f16(a2, bh[0][2], acc0, 0, 0, 0);
        acc1 = __builtin_amdgcn_mfma_f32_32x32x16_f16(a2, bh[1][2], acc1, 0, 0, 0);
        acc0 = __builtin_amdgcn_mfma_f32_32x32x16_f16(a3, bh[0][3], acc0, 0, 0, 0);
        acc1 = __builtin_amdgcn_mfma_f32_32x32x16_f16(a3, bh[1][3], acc1, 0, 0, 0);

        acc0 = __builtin_amdgcn_mfma_f32_32x32x16_f16(a0, bl[0][0], acc0, 0, 0, 0);
        acc1 = __builtin_amdgcn_mfma_f32_32x32x16_f16(a0, bl[1][0], acc1, 0, 0, 0);
        acc0 = __builtin_amdgcn_mfma_f32_32x32x16_f16(a1, bl[0][1], acc0, 0, 0, 0);
        acc1 = __builtin_amdgcn_mfma_f32_32x32x16_f16(a1, bl[1][1], acc1, 0, 0, 0);
        acc0 = __builtin_amdgcn_mfma_f32_32x32x16_f16(a2, bl[0][2], acc0, 0, 0, 0);
        acc1 = __builtin_amdgcn_mfma_f32_32x32x16_f16(a2, bl[1][2], acc1, 0, 0, 0);
        acc0 = __builtin_amdgcn_mfma_f32_32x32x16_f16(a3, bl[0][3], acc0, 0, 0, 0);
        acc1 = __builtin_amdgcn_mfma_f32_32x32x16_f16(a3, bl[1][3], acc1, 0, 0, 0);

        acc0 = __builtin_amdgcn_mfma_f32_32x32x16_f16(a4, bh[0][0], acc0, 0, 0, 0);
        acc1 = __builtin_amdgcn_mfma_f32_32x32x16_f16(a4, bh[1][0], acc1, 0, 0, 0);
        acc0 = __builtin_amdgcn_mfma_f32_32x32x16_f16(a5, bh[0][1], acc0, 0, 0, 0);
        acc1 = __builtin_amdgcn_mfma_f32_32x32x16_f16(a5, bh[1][1], acc1, 0, 0, 0);
        acc0 = __builtin_amdgcn_mfma_f32_32x32x16_f16(a6, bh[0][2], acc0, 0, 0, 0);
        acc1 = __builtin_amdgcn_mfma_f32_32x32x16_f16(a6, bh[1][2], acc1, 0, 0, 0);
        acc0 = __builtin_amdgcn_mfma_f32_32x32x16_f16(a7, bh[0][3], acc0, 0, 0, 0);
        acc1 = __builtin_amdgcn_mfma_f32_32x32x16_f16(a7, bh[1][3], acc1, 0, 0, 0);

        // packed-slot top-2 tracking: slot = (tile&15)<<4 | r, low 8 mantissa bits
        const int tcur = (rot + i) & 15;
        #pragma unroll
        for (int r = 0; r < 16; ++r) {
            const unsigned slot = (unsigned)((tcur << 4) | r);
            const float s0 = __uint_as_float((__float_as_uint(acc0[r]) & 0xFFFFFF00u) | slot);
            b20 = __builtin_amdgcn_fmed3f(s0, bv0, b20);
            bv0 = fminf(bv0, s0);
            const float s1 = __uint_as_float((__float_as_uint(acc1[r]) & 0xFFFFFF00u) | slot);
            b21 = __builtin_amdgcn_fmed3f(s1, bv1, b21);
            bv1 = fminf(bv1, s1);
        }
        a0 = n0; a1 = n1; a2 = n2; a3 = n3;
        a4 = n4; a5 = n5; a6 = n6; a7 = n7; ae = ne;
    }

    // ---- cross-half-row merge (lane <-> lane^32), decode cw, stash to LDS ----
    #pragma unroll
    for (int ct = 0; ct < 2; ++ct) {
        const float bv = ct ? bv1 : bv0;
        const float b2 = ct ? b21 : b20;
        const float obv = __shfl_xor(bv, 32, 64);
        const float ob2 = __shfl_xor(b2, 32, 64);
        const float B1 = fminf(bv, obv);
        const float B2 = fminf(fmaxf(bv, obv), fminf(b2, ob2));
        const int   lho = (obv < bv) ? (lh ^ 1) : lh;   // tie keeps own (lh=0 wins)
        const unsigned slot = __float_as_uint(B1) & 255u;
        const int r  = slot & 15;
        const int tt = slot >> 4;
        const int cw = (h * 16 + tt) * 32 + (r & 3) + 8 * (r >> 2) + 4 * lho;
        if (lane < 32) {
            s_pv[h][g][ct * 32 + lane] = B1;
            s_p2[h][g][ct * 32 + lane] = B2;
            s_pk[h][g][ct * 32 + lane] = cw;
        }
    }
    __syncthreads();

    // ---- merge the two K-halves per token; flag near-ties ----
    if (tid < 128) {
        const int g2 = tid >> 6, tk = tid & 63;
        const float v0 = s_pv[0][g2][tk], v1 = s_pv[1][g2][tk];
        const bool  w1 = v1 < v0;                       // tie -> h=0 (lower cw)
        const float B1 = fminf(v0, v1);
        const float B2 = fminf(fmaxf(v0, v1), fminf(s_p2[0][g2][tk], s_p2[1][g2][tk]));
        s_idx[tid] = w1 ? s_pk[1][g2][tk] : s_pk[0][g2][tk];
        if (B2 - B1 < EPS) {
            const int p = atomicAdd(&s_cnt, 1);
            s_list[p] = tid;
        }
    }
    __syncthreads();

    // ---- exact fp32 rescan, block-cooperative (rare: ~2.5e-4 of tokens) ----
    {
        const int cnt = s_cnt;
        const int rr  = tid >> 2;   // codeword row within 64-chunk
        const int c   = tid & 3;    // d-quarter
        for (int ii = 0; ii < cnt; ++ii) {
            const int tl = s_list[ii];
            if (tid < 64)
                s_xf[tid] = input[(size_t)b * DHW + (size_t)tid * HW + (hwb + tl)];
            __syncthreads();
            const float4* xs4 = (const float4*)&s_xf[c * 16];
            const float4 x0 = xs4[0], x1 = xs4[1], x2 = xs4[2], x3 = xs4[3];
            float bestv = INF; int bestk = K;
            #pragma unroll 4
            for (int i = 0; i < 16; ++i) {
                const int k = i * 64 + rr;                 // ascending per thread
                const float4* c4 = (const float4*)(codebook + (size_t)k * D + c * 16);
                const float4 c0 = c4[0], c1 = c4[1], c2 = c4[2], c3 = c4[3];
                float p0 = 0.f, p1 = 0.f, p2 = 0.f, p3 = 0.f;
                p0 = fmaf(x0.x, c0.x, p0); p0 = fmaf(x0.y, c0.y, p0);
                p0 = fmaf(x0.z, c0.z, p0); p0 = fmaf(x0.w, c0.w, p0);
                p1 = fmaf(x1.x, c1.x, p1); p1 = fmaf(x1.y, c1.y, p1);
                p1 = fmaf(x1.z, c1.z, p1); p1 = fmaf(x1.w, c1.w, p1);
                p2 = fmaf(x2.x, c2.x, p2); p2 = fmaf(x2.y, c2.y, p2);
                p2 = fmaf(x2.z, c2.z, p2); p2 = fmaf(x2.w, c2.w, p2);
                p3 = fmaf(x3.x, c3.x, p3); p3 = fmaf(x3.y, c3.y, p3);
                p3 = fmaf(x3.z, c3.z, p3); p3 = fmaf(x3.w, c3.w, p3);
                float dp = (p0 + p1) + (p2 + p3);
                dp += __shfl_xor(dp, 1, 64);               // sum over d-quarters
                dp += __shfl_xor(dp, 2, 64);
                const float s = fmaf(-2.0f, dp, esq[k]);
                if (s < bestv) { bestv = s; bestk = k; }
            }
            #pragma unroll
            for (int off = 4; off <= 32; off <<= 1) {      // reduce over rows in wave
                const float ov = __shfl_xor(bestv, off, 64);
                const int   ok = __shfl_xor(bestk, off, 64);
                if (ov < bestv || (ov == bestv && ok < bestk)) { bestv = ov; bestk = ok; }
            }
            if (lane == 0) { s_redv[q] = bestv; s_redk[q] = bestk; }
            __syncthreads();
            if (tid == 0) {
                float bb = s_redv[0]; int bk = s_redk[0];
                #pragma unroll
                for (int w = 1; w < 4; ++w) {
                    const float v = s_redv[w]; const int kk = s_redk[w];
                    if (v < bb || (v == bb && kk < bk)) { bb = v; bk = kk; }
                }
                s_idx[tl] = bk;
            }
            __syncthreads();
        }
    }

    // ---- epilogue: per-channel coalesced stores (thread = token x d-half) ----
    {
        const int token = tid & 127;
        const int dh    = tid >> 7;                        // 0/1
        const int idx   = s_idx[token];
        const float4* c4 = (const float4*)(codebook + (size_t)idx * D + dh * 32);
        float4 cr[8];
        #pragma unroll
        for (int j = 0; j < 8; ++j) cr[j] = c4[j];
        float* ob = out + (size_t)b * DHW + (size_t)dh * 32 * HW + hwb + token;
        #pragma unroll
        for (int j = 0; j < 8; ++j) {
            ob[(size_t)(4 * j + 0) * HW] = cr[j].x;
            ob[(size_t)(4 * j + 1) * HW] = cr[j].y;
            ob[(size_t)(4 * j + 2) * HW] = cr[j].z;
            ob[(size_t)(4 * j + 3) * HW] = cr[j].w;
        }
        if (tid < 128) out[OUT_ELEMS + tok0 + tid] = (float)s_idx[tid];
    }
}

extern "C" void kernel_launch(void* const* d_in, const int* in_sizes, int n_in,
                              void* d_out, int out_size, void* d_ws, size_t ws_size,
                              hipStream_t stream) {
    const float* input    = (const float*)d_in[0];
    const float* codebook = (const float*)d_in[1];
    float* out            = (float*)d_out;

    _Float16* CH  = (_Float16*)d_ws;                   // 294912 B
    float*    esq = (float*)((char*)d_ws + 294912);    // 4096 B

    vq_prep<<<76, 256, 0, stream>>>(codebook, CH, esq);
    vq_scan<<<512, 256, 0, stream>>>(input, codebook, CH, esq, out);
}